// Round 7
// baseline (193.607 us; speedup 1.0000x reference)
//
#include <hip/hip_runtime.h>
#include <math.h>

#define D_DIM   128
#define NCHART  64
#define PADR    132      // padded row stride (floats); 132*4B = 16B-aligned rows
#define BPC     8        // blocks per chart
#define NS      4        // samples per wave batch
#define MAXNORM 0.99f

typedef float f32x4 __attribute__((ext_vector_type(4)));

__device__ __forceinline__ float wave_sum(float v) {
#pragma unroll
  for (int m = 32; m > 0; m >>= 1) v += __shfl_xor(v, m, 64);
  return v;
}

// ws layout (ints): [0..63] tgt_off | [64..127] tgt_cnt | [128..191] src_off |
//                   [192..255] src_cnt | [256..256+B) tgt_list | [256+B..256+2B) src_list
__global__ __launch_bounds__(256) void k_setup(
    const int* __restrict__ src, const int* __restrict__ tgt,
    int* __restrict__ ws, int B)
{
  __shared__ int cntT[NCHART], cntS[NCHART], offT[NCHART], offS[NCHART];
  const int tid = threadIdx.x;
  if (tid < NCHART) { cntT[tid] = 0; cntS[tid] = 0; }
  __syncthreads();
  for (int b = tid; b < B; b += 256) {
    atomicAdd(&cntT[tgt[b]], 1);
    atomicAdd(&cntS[src[b]], 1);
  }
  __syncthreads();
  if (tid == 0) {
    int aT = 0, aS = 0;
    for (int c = 0; c < NCHART; ++c) {
      offT[c] = aT; aT += cntT[c];
      offS[c] = aS; aS += cntS[c];
    }
  }
  __syncthreads();
  if (tid < NCHART) {
    ws[tid]            = offT[tid];
    ws[NCHART + tid]   = cntT[tid];
    ws[2*NCHART + tid] = offS[tid];
    ws[3*NCHART + tid] = cntS[tid];
  }
  if (tid < NCHART) { cntT[tid] = 0; cntS[tid] = 0; }
  __syncthreads();
  int* tlist = ws + 4*NCHART;
  int* slist = tlist + B;
  for (int b = tid; b < B; b += 256) {
    int ct = tgt[b]; int p = atomicAdd(&cntT[ct], 1); tlist[offT[ct] + p] = b;
    int cs = src[b]; int r = atomicAdd(&cntS[cs], 1); slist[offS[cs] + r] = b;
  }
}

// ---------------- stage 1: z_global = mobius(-proj(c_src), proj(z)); v = R_tgt @ z_global
__global__ __launch_bounds__(256) void k_stage1(
    const float* __restrict__ z_n, const float* __restrict__ centers,
    const float* __restrict__ rot, const int* __restrict__ src_idx,
    const int* __restrict__ ws, float* __restrict__ vout)
{
  __shared__ float R[D_DIM * PADR];     // 67.6 KB
  __shared__ float zs[4][NS][D_DIM];    // 8 KB

  const int tid = threadIdx.x;
  const int chart = blockIdx.x >> 3;
  const int q = blockIdx.x & 7;
  const int n = ws[NCHART + chart];
  if (q * 4 * NS >= n) return;          // block-uniform early exit
  const int base = ws[chart];
  const int* __restrict__ tlist = ws + 4*NCHART;

  const f32x4* G4 = (const f32x4*)(rot + (size_t)chart * D_DIM * D_DIM);
  for (int g = tid; g < 4096; g += 256) {
    int r = g >> 5, J = g & 31;
    *(f32x4*)&R[r * PADR + 4 * J] = G4[g];
  }
  __syncthreads();

  const int w = tid >> 6, l = tid & 63;

  // wave-slot = q*4+w in [0,32); starts {0,4,...,124}, stride 128 -> full coverage
  for (int s0 = (q * 4 + w) * NS; s0 < n; s0 += 32 * NS) {
    const int kmax = min(NS, n - s0);   // wave-uniform
    int bs[NS];
#pragma unroll
    for (int k = 0; k < NS; ++k) {
      if (k < kmax) {
        int b = tlist[base + s0 + k];
        bs[k] = b;
        float a  = z_n[(size_t)b * D_DIM + l];
        float bb = z_n[(size_t)b * D_DIM + l + 64];
        float nz = sqrtf(wave_sum(a * a + bb * bb));
        if (nz > MAXNORM) { float sc = MAXNORM / nz; a *= sc; bb *= sc; }

        int si = src_idx[b];
        float c0 = centers[(size_t)si * D_DIM + l];
        float c1 = centers[(size_t)si * D_DIM + l + 64];
        float ncn = sqrtf(wave_sum(c0 * c0 + c1 * c1));
        if (ncn > MAXNORM) { float sc = MAXNORM / ncn; c0 *= sc; c1 *= sc; }
        c0 = -c0; c1 = -c1;                        // x = -c_source

        float x2 = wave_sum(c0 * c0 + c1 * c1);
        float y2 = wave_sum(a * a + bb * bb);
        float xy = wave_sum(c0 * a + c1 * bb);
        float nx  = 1.0f + 2.0f * xy + y2;
        float ny  = 1.0f - x2;
        float inv = 1.0f / fmaxf(1.0f + 2.0f * xy + x2 * y2, 1e-15f);
        zs[w][k][l]      = (nx * c0 + ny * a)  * inv;
        zs[w][k][l + 64] = (nx * c1 + ny * bb) * inv;
      }
    }
    asm volatile("s_waitcnt lgkmcnt(0)" ::: "memory");

    // v_i = sum_j R[i][j] z_j ; NS samples share the R reads.
    // k >= kmax slots read stale/garbage LDS -> acc garbage, never stored.
    float acc0[NS] = {}, acc1[NS] = {};
#pragma unroll
    for (int Jg = 0; Jg < 32; ++Jg) {
      f32x4 a0 = *(const f32x4*)&R[l * PADR + 4 * Jg];
      f32x4 a1 = *(const f32x4*)&R[(l + 64) * PADR + 4 * Jg];
#pragma unroll
      for (int k = 0; k < NS; ++k) {
        f32x4 zv = *(const f32x4*)&zs[w][k][4 * Jg];
#pragma unroll
        for (int m = 0; m < 4; ++m) {
          acc0[k] = fmaf(a0[m], zv[m], acc0[k]);
          acc1[k] = fmaf(a1[m], zv[m], acc1[k]);
        }
      }
    }
#pragma unroll
    for (int k = 0; k < NS; ++k) {
      if (k < kmax) {
        vout[(size_t)bs[k] * D_DIM + l]      = acc0[k];
        vout[(size_t)bs[k] * D_DIM + l + 64] = acc1[k];
      }
    }
  }
}

// ---------------- stage 2: w = R_src^T @ v; out = proj(mobius(proj(c_tgt), w))
__global__ __launch_bounds__(256) void k_stage2(
    const float* __restrict__ centers, const float* __restrict__ rot,
    const int* __restrict__ tgt_idx, const int* __restrict__ ws,
    float* __restrict__ io, int B)
{
  __shared__ float R[D_DIM * PADR];
  __shared__ float vs[4][NS][D_DIM];

  const int tid = threadIdx.x;
  const int chart = blockIdx.x >> 3;
  const int q = blockIdx.x & 7;
  const int n = ws[3*NCHART + chart];
  if (q * 4 * NS >= n) return;
  const int base = ws[2*NCHART + chart];
  const int* __restrict__ slist = ws + 4*NCHART + B;

  const f32x4* G4 = (const f32x4*)(rot + (size_t)chart * D_DIM * D_DIM);
  for (int g = tid; g < 4096; g += 256) {
    int r = g >> 5, J = g & 31;
    *(f32x4*)&R[r * PADR + 4 * J] = G4[g];
  }
  __syncthreads();

  const int w = tid >> 6, l = tid & 63;

  for (int s0 = (q * 4 + w) * NS; s0 < n; s0 += 32 * NS) {
    const int kmax = min(NS, n - s0);
    int bs[NS];
#pragma unroll
    for (int k = 0; k < NS; ++k) {
      if (k < kmax) {
        int b = slist[base + s0 + k];
        bs[k] = b;
        vs[w][k][l]      = io[(size_t)b * D_DIM + l];
        vs[w][k][l + 64] = io[(size_t)b * D_DIM + l + 64];
      }
    }
    asm volatile("s_waitcnt lgkmcnt(0)" ::: "memory");

    // w_i = sum_j R[j][i] v_j ; column reads (2 lanes/bank = free), NS shares reads
    float acc0[NS] = {}, acc1[NS] = {};
#pragma unroll
    for (int Jg = 0; Jg < 32; ++Jg) {
      float r0[4], r1[4];
#pragma unroll
      for (int m = 0; m < 4; ++m) {
        r0[m] = R[(4 * Jg + m) * PADR + l];
        r1[m] = R[(4 * Jg + m) * PADR + l + 64];
      }
#pragma unroll
      for (int k = 0; k < NS; ++k) {
        f32x4 vv = *(const f32x4*)&vs[w][k][4 * Jg];
#pragma unroll
        for (int m = 0; m < 4; ++m) {
          acc0[k] = fmaf(r0[m], vv[m], acc0[k]);
          acc1[k] = fmaf(r1[m], vv[m], acc1[k]);
        }
      }
    }

#pragma unroll
    for (int k = 0; k < NS; ++k) {
      if (k < kmax) {
        int b = bs[k];
        int ti = tgt_idx[b];
        float c0 = centers[(size_t)ti * D_DIM + l];
        float c1 = centers[(size_t)ti * D_DIM + l + 64];
        float ncn = sqrtf(wave_sum(c0 * c0 + c1 * c1));
        if (ncn > MAXNORM) { float sc = MAXNORM / ncn; c0 *= sc; c1 *= sc; }

        float w0 = acc0[k], w1 = acc1[k];
        float x2 = wave_sum(c0 * c0 + c1 * c1);
        float y2 = wave_sum(w0 * w0 + w1 * w1);
        float xy = wave_sum(c0 * w0 + c1 * w1);
        float nx  = 1.0f + 2.0f * xy + y2;
        float ny  = 1.0f - x2;
        float inv = 1.0f / fmaxf(1.0f + 2.0f * xy + x2 * y2, 1e-15f);
        float o0 = (nx * c0 + ny * w0) * inv;
        float o1 = (nx * c1 + ny * w1) * inv;

        float no = sqrtf(wave_sum(o0 * o0 + o1 * o1));
        if (no > MAXNORM) { float sc = MAXNORM / no; o0 *= sc; o1 *= sc; }

        io[(size_t)b * D_DIM + l]      = o0;
        io[(size_t)b * D_DIM + l + 64] = o1;
      }
    }
  }
}

extern "C" void kernel_launch(void* const* d_in, const int* in_sizes, int n_in,
                              void* d_out, int out_size, void* d_ws, size_t ws_size,
                              hipStream_t stream) {
  const float* z_n     = (const float*)d_in[0];
  const float* centers = (const float*)d_in[1];
  const float* rot     = (const float*)d_in[2];
  const int*   src     = (const int*)d_in[3];
  const int*   tgt     = (const int*)d_in[4];
  float* out = (float*)d_out;
  int* ws = (int*)d_ws;
  const int B = in_sizes[3];

  k_setup<<<dim3(1), dim3(256), 0, stream>>>(src, tgt, ws, B);
  dim3 grid(NCHART * BPC), block(256);
  k_stage1<<<grid, block, 0, stream>>>(z_n, centers, rot, src, ws, out);
  k_stage2<<<grid, block, 0, stream>>>(centers, rot, tgt, ws, out, B);
}

// Round 8
// 101.956 us; speedup vs baseline: 1.8989x; 1.8989x over previous
//
#include <hip/hip_runtime.h>
#include <math.h>

#define D_DIM   128
#define NCHART  64
#define PADR    132      // padded row stride (floats); 132*4B = 16B-aligned rows
#define BPC     8        // blocks per chart
#define NS      2        // samples per wave batch (NS=4 spilled: VGPR 256, 81MB scratch writes)
#define MAXNORM 0.99f

typedef float f32x4 __attribute__((ext_vector_type(4)));

__device__ __forceinline__ float wave_sum(float v) {
#pragma unroll
  for (int m = 32; m > 0; m >>= 1) v += __shfl_xor(v, m, 64);
  return v;
}

// ws layout (ints): [0..63] tgt_off | [64..127] tgt_cnt | [128..191] src_off |
//                   [192..255] src_cnt | [256..256+B) tgt_list | [256+B..256+2B) src_list
__global__ __launch_bounds__(256) void k_setup(
    const int* __restrict__ src, const int* __restrict__ tgt,
    int* __restrict__ ws, int B)
{
  __shared__ int cntT[NCHART], cntS[NCHART], offT[NCHART], offS[NCHART];
  const int tid = threadIdx.x;
  if (tid < NCHART) { cntT[tid] = 0; cntS[tid] = 0; }
  __syncthreads();
  for (int b = tid; b < B; b += 256) {
    atomicAdd(&cntT[tgt[b]], 1);
    atomicAdd(&cntS[src[b]], 1);
  }
  __syncthreads();
  if (tid == 0) {
    int aT = 0, aS = 0;
    for (int c = 0; c < NCHART; ++c) {
      offT[c] = aT; aT += cntT[c];
      offS[c] = aS; aS += cntS[c];
    }
  }
  __syncthreads();
  if (tid < NCHART) {
    ws[tid]            = offT[tid];
    ws[NCHART + tid]   = cntT[tid];
    ws[2*NCHART + tid] = offS[tid];
    ws[3*NCHART + tid] = cntS[tid];
  }
  if (tid < NCHART) { cntT[tid] = 0; cntS[tid] = 0; }
  __syncthreads();
  int* tlist = ws + 4*NCHART;
  int* slist = tlist + B;
  for (int b = tid; b < B; b += 256) {
    int ct = tgt[b]; int p = atomicAdd(&cntT[ct], 1); tlist[offT[ct] + p] = b;
    int cs = src[b]; int r = atomicAdd(&cntS[cs], 1); slist[offS[cs] + r] = b;
  }
}

// ---------------- stage 1: z_global = mobius(-proj(c_src), proj(z)); v = R_tgt @ z_global
__global__ __launch_bounds__(256) void k_stage1(
    const float* __restrict__ z_n, const float* __restrict__ centers,
    const float* __restrict__ rot, const int* __restrict__ src_idx,
    const int* __restrict__ ws, float* __restrict__ vout)
{
  __shared__ float R[D_DIM * PADR];     // 67.6 KB
  __shared__ float zs[4][NS][D_DIM];    // 4 KB

  const int tid = threadIdx.x;
  const int chart = blockIdx.x >> 3;
  const int q = blockIdx.x & 7;
  const int n = ws[NCHART + chart];
  if (q * 4 * NS >= n) return;          // block-uniform early exit
  const int base = ws[chart];
  const int* __restrict__ tlist = ws + 4*NCHART;

  const f32x4* G4 = (const f32x4*)(rot + (size_t)chart * D_DIM * D_DIM);
  for (int g = tid; g < 4096; g += 256) {
    int r = g >> 5, J = g & 31;
    *(f32x4*)&R[r * PADR + 4 * J] = G4[g];
  }
  __syncthreads();

  const int w = tid >> 6, l = tid & 63;

  // wave-slot = q*4+w in [0,32); starts {0,2,...,62}, stride 64 -> full coverage
  for (int s0 = (q * 4 + w) * NS; s0 < n; s0 += 32 * NS) {
    const int kmax = min(NS, n - s0);   // wave-uniform
    int bs[NS];
#pragma unroll
    for (int k = 0; k < NS; ++k) {
      if (k < kmax) {
        int b = tlist[base + s0 + k];
        bs[k] = b;
        float a  = z_n[(size_t)b * D_DIM + l];
        float bb = z_n[(size_t)b * D_DIM + l + 64];
        float nz = sqrtf(wave_sum(a * a + bb * bb));
        if (nz > MAXNORM) { float sc = MAXNORM / nz; a *= sc; bb *= sc; }

        int si = src_idx[b];
        float c0 = centers[(size_t)si * D_DIM + l];
        float c1 = centers[(size_t)si * D_DIM + l + 64];
        float ncn = sqrtf(wave_sum(c0 * c0 + c1 * c1));
        if (ncn > MAXNORM) { float sc = MAXNORM / ncn; c0 *= sc; c1 *= sc; }
        c0 = -c0; c1 = -c1;                        // x = -c_source

        float x2 = wave_sum(c0 * c0 + c1 * c1);
        float y2 = wave_sum(a * a + bb * bb);
        float xy = wave_sum(c0 * a + c1 * bb);
        float nx  = 1.0f + 2.0f * xy + y2;
        float ny  = 1.0f - x2;
        float inv = 1.0f / fmaxf(1.0f + 2.0f * xy + x2 * y2, 1e-15f);
        zs[w][k][l]      = (nx * c0 + ny * a)  * inv;
        zs[w][k][l + 64] = (nx * c1 + ny * bb) * inv;
      }
    }
    asm volatile("s_waitcnt lgkmcnt(0)" ::: "memory");

    // v_i = sum_j R[i][j] z_j ; NS samples share the R reads.
    // k >= kmax slots read stale/garbage LDS -> acc garbage, never stored.
    float acc0[NS] = {}, acc1[NS] = {};
#pragma unroll
    for (int Jg = 0; Jg < 32; ++Jg) {
      f32x4 a0 = *(const f32x4*)&R[l * PADR + 4 * Jg];
      f32x4 a1 = *(const f32x4*)&R[(l + 64) * PADR + 4 * Jg];
#pragma unroll
      for (int k = 0; k < NS; ++k) {
        f32x4 zv = *(const f32x4*)&zs[w][k][4 * Jg];
#pragma unroll
        for (int m = 0; m < 4; ++m) {
          acc0[k] = fmaf(a0[m], zv[m], acc0[k]);
          acc1[k] = fmaf(a1[m], zv[m], acc1[k]);
        }
      }
    }
#pragma unroll
    for (int k = 0; k < NS; ++k) {
      if (k < kmax) {
        vout[(size_t)bs[k] * D_DIM + l]      = acc0[k];
        vout[(size_t)bs[k] * D_DIM + l + 64] = acc1[k];
      }
    }
  }
}

// ---------------- stage 2: w = R_src^T @ v; out = proj(mobius(proj(c_tgt), w))
__global__ __launch_bounds__(256) void k_stage2(
    const float* __restrict__ centers, const float* __restrict__ rot,
    const int* __restrict__ tgt_idx, const int* __restrict__ ws,
    float* __restrict__ io, int B)
{
  __shared__ float R[D_DIM * PADR];
  __shared__ float vs[4][NS][D_DIM];

  const int tid = threadIdx.x;
  const int chart = blockIdx.x >> 3;
  const int q = blockIdx.x & 7;
  const int n = ws[3*NCHART + chart];
  if (q * 4 * NS >= n) return;
  const int base = ws[2*NCHART + chart];
  const int* __restrict__ slist = ws + 4*NCHART + B;

  const f32x4* G4 = (const f32x4*)(rot + (size_t)chart * D_DIM * D_DIM);
  for (int g = tid; g < 4096; g += 256) {
    int r = g >> 5, J = g & 31;
    *(f32x4*)&R[r * PADR + 4 * J] = G4[g];
  }
  __syncthreads();

  const int w = tid >> 6, l = tid & 63;

  for (int s0 = (q * 4 + w) * NS; s0 < n; s0 += 32 * NS) {
    const int kmax = min(NS, n - s0);
    int bs[NS];
#pragma unroll
    for (int k = 0; k < NS; ++k) {
      if (k < kmax) {
        int b = slist[base + s0 + k];
        bs[k] = b;
        vs[w][k][l]      = io[(size_t)b * D_DIM + l];
        vs[w][k][l + 64] = io[(size_t)b * D_DIM + l + 64];
      }
    }
    asm volatile("s_waitcnt lgkmcnt(0)" ::: "memory");

    // w_i = sum_j R[j][i] v_j ; column reads (2 lanes/bank = free), NS shares reads
    float acc0[NS] = {}, acc1[NS] = {};
#pragma unroll
    for (int Jg = 0; Jg < 32; ++Jg) {
      float r0[4], r1[4];
#pragma unroll
      for (int m = 0; m < 4; ++m) {
        r0[m] = R[(4 * Jg + m) * PADR + l];
        r1[m] = R[(4 * Jg + m) * PADR + l + 64];
      }
#pragma unroll
      for (int k = 0; k < NS; ++k) {
        f32x4 vv = *(const f32x4*)&vs[w][k][4 * Jg];
#pragma unroll
        for (int m = 0; m < 4; ++m) {
          acc0[k] = fmaf(r0[m], vv[m], acc0[k]);
          acc1[k] = fmaf(r1[m], vv[m], acc1[k]);
        }
      }
    }

#pragma unroll
    for (int k = 0; k < NS; ++k) {
      if (k < kmax) {
        int b = bs[k];
        int ti = tgt_idx[b];
        float c0 = centers[(size_t)ti * D_DIM + l];
        float c1 = centers[(size_t)ti * D_DIM + l + 64];
        float ncn = sqrtf(wave_sum(c0 * c0 + c1 * c1));
        if (ncn > MAXNORM) { float sc = MAXNORM / ncn; c0 *= sc; c1 *= sc; }

        float w0 = acc0[k], w1 = acc1[k];
        float x2 = wave_sum(c0 * c0 + c1 * c1);
        float y2 = wave_sum(w0 * w0 + w1 * w1);
        float xy = wave_sum(c0 * w0 + c1 * w1);
        float nx  = 1.0f + 2.0f * xy + y2;
        float ny  = 1.0f - x2;
        float inv = 1.0f / fmaxf(1.0f + 2.0f * xy + x2 * y2, 1e-15f);
        float o0 = (nx * c0 + ny * w0) * inv;
        float o1 = (nx * c1 + ny * w1) * inv;

        float no = sqrtf(wave_sum(o0 * o0 + o1 * o1));
        if (no > MAXNORM) { float sc = MAXNORM / no; o0 *= sc; o1 *= sc; }

        io[(size_t)b * D_DIM + l]      = o0;
        io[(size_t)b * D_DIM + l + 64] = o1;
      }
    }
  }
}

extern "C" void kernel_launch(void* const* d_in, const int* in_sizes, int n_in,
                              void* d_out, int out_size, void* d_ws, size_t ws_size,
                              hipStream_t stream) {
  const float* z_n     = (const float*)d_in[0];
  const float* centers = (const float*)d_in[1];
  const float* rot     = (const float*)d_in[2];
  const int*   src     = (const int*)d_in[3];
  const int*   tgt     = (const int*)d_in[4];
  float* out = (float*)d_out;
  int* ws = (int*)d_ws;
  const int B = in_sizes[3];

  k_setup<<<dim3(1), dim3(256), 0, stream>>>(src, tgt, ws, B);
  dim3 grid(NCHART * BPC), block(256);
  k_stage1<<<grid, block, 0, stream>>>(z_n, centers, rot, src, ws, out);
  k_stage2<<<grid, block, 0, stream>>>(centers, rot, tgt, ws, out, B);
}

// Round 9
// 56.666 us; speedup vs baseline: 3.4166x; 1.7993x over previous
//
#include <hip/hip_runtime.h>
#include <math.h>

#define D_DIM   128
#define NCHART  64
#define PADR    132      // padded row stride (floats); 132*4B = 16B-aligned rows
#define BPC     8        // blocks per chart
#define NS      2        // samples per wave batch (NS=4 spilled: VGPR 256, 81MB scratch writes)
#define MAXNORM 0.99f

typedef float f32x4 __attribute__((ext_vector_type(4)));

__device__ __forceinline__ float wave_sum(float v) {
#pragma unroll
  for (int m = 32; m > 0; m >>= 1) v += __shfl_xor(v, m, 64);
  return v;
}

// ws layout (ints): [0..63] tgt_off | [64..127] tgt_cnt | [128..191] src_off |
//                   [192..255] src_cnt | [256..256+B) tgt_list | [256+B..256+2B) src_list
__global__ __launch_bounds__(256) void k_setup(
    const int* __restrict__ src, const int* __restrict__ tgt,
    int* __restrict__ ws, int B)
{
  __shared__ int cntT[NCHART], cntS[NCHART], offT[NCHART], offS[NCHART];
  const int tid = threadIdx.x;
  if (tid < NCHART) { cntT[tid] = 0; cntS[tid] = 0; }
  __syncthreads();
  for (int b = tid; b < B; b += 256) {
    atomicAdd(&cntT[tgt[b]], 1);
    atomicAdd(&cntS[src[b]], 1);
  }
  __syncthreads();
  if (tid == 0) {
    int aT = 0, aS = 0;
    for (int c = 0; c < NCHART; ++c) {
      offT[c] = aT; aT += cntT[c];
      offS[c] = aS; aS += cntS[c];
    }
  }
  __syncthreads();
  if (tid < NCHART) {
    ws[tid]            = offT[tid];
    ws[NCHART + tid]   = cntT[tid];
    ws[2*NCHART + tid] = offS[tid];
    ws[3*NCHART + tid] = cntS[tid];
  }
  if (tid < NCHART) { cntT[tid] = 0; cntS[tid] = 0; }
  __syncthreads();
  int* tlist = ws + 4*NCHART;
  int* slist = tlist + B;
  for (int b = tid; b < B; b += 256) {
    int ct = tgt[b]; int p = atomicAdd(&cntT[ct], 1); tlist[offT[ct] + p] = b;
    int cs = src[b]; int r = atomicAdd(&cntS[cs], 1); slist[offS[cs] + r] = b;
  }
}

// ---------------- stage 1: z_global = mobius(-proj(c_src), proj(z)); v = R_tgt @ z_global
__global__ __launch_bounds__(256) void k_stage1(
    const float* __restrict__ z_n, const float* __restrict__ centers,
    const float* __restrict__ rot, const int* __restrict__ src_idx,
    const int* __restrict__ ws, float* __restrict__ vout)
{
  __shared__ float R[D_DIM * PADR];     // 67.6 KB
  __shared__ float zs[4][NS][D_DIM];    // 4 KB

  const int tid = threadIdx.x;
  const int chart = blockIdx.x >> 3;
  const int q = blockIdx.x & 7;
  const int n = ws[NCHART + chart];
  if (q * 4 * NS >= n) return;          // block-uniform early exit
  const int base = ws[chart];
  const int* __restrict__ tlist = ws + 4*NCHART;

  const f32x4* G4 = (const f32x4*)(rot + (size_t)chart * D_DIM * D_DIM);
  for (int g = tid; g < 4096; g += 256) {
    int r = g >> 5, J = g & 31;
    *(f32x4*)&R[r * PADR + 4 * J] = G4[g];
  }
  __syncthreads();

  const int w = tid >> 6, l = tid & 63;

  // wave-slot = q*4+w in [0,32); starts {0,2,...,62}, stride 64 -> full coverage
  for (int s0 = (q * 4 + w) * NS; s0 < n; s0 += 32 * NS) {
    const int kmax = min(NS, n - s0);   // wave-uniform
    int bs[NS];
#pragma unroll
    for (int k = 0; k < NS; ++k) {
      if (k < kmax) {
        int b = tlist[base + s0 + k];
        bs[k] = b;
        float a  = z_n[(size_t)b * D_DIM + l];
        float bb = z_n[(size_t)b * D_DIM + l + 64];
        float nz = sqrtf(wave_sum(a * a + bb * bb));
        if (nz > MAXNORM) { float sc = MAXNORM / nz; a *= sc; bb *= sc; }

        int si = src_idx[b];
        float c0 = centers[(size_t)si * D_DIM + l];
        float c1 = centers[(size_t)si * D_DIM + l + 64];
        float ncn = sqrtf(wave_sum(c0 * c0 + c1 * c1));
        if (ncn > MAXNORM) { float sc = MAXNORM / ncn; c0 *= sc; c1 *= sc; }
        c0 = -c0; c1 = -c1;                        // x = -c_source

        float x2 = wave_sum(c0 * c0 + c1 * c1);
        float y2 = wave_sum(a * a + bb * bb);
        float xy = wave_sum(c0 * a + c1 * bb);
        float nx  = 1.0f + 2.0f * xy + y2;
        float ny  = 1.0f - x2;
        float inv = 1.0f / fmaxf(1.0f + 2.0f * xy + x2 * y2, 1e-15f);
        zs[w][k][l]      = (nx * c0 + ny * a)  * inv;
        zs[w][k][l + 64] = (nx * c1 + ny * bb) * inv;
      }
    }
    asm volatile("s_waitcnt lgkmcnt(0)" ::: "memory");

    // v_i = sum_j R[i][j] z_j ; NS samples share the R reads.
    // Bounded unroll: full unroll of Jg=32 hoisted all LDS reads -> 256 VGPR + spill.
    float acc0[NS] = {}, acc1[NS] = {};
#pragma unroll 4
    for (int Jg = 0; Jg < 32; ++Jg) {
      f32x4 a0 = *(const f32x4*)&R[l * PADR + 4 * Jg];
      f32x4 a1 = *(const f32x4*)&R[(l + 64) * PADR + 4 * Jg];
#pragma unroll
      for (int k = 0; k < NS; ++k) {
        f32x4 zv = *(const f32x4*)&zs[w][k][4 * Jg];
#pragma unroll
        for (int m = 0; m < 4; ++m) {
          acc0[k] = fmaf(a0[m], zv[m], acc0[k]);
          acc1[k] = fmaf(a1[m], zv[m], acc1[k]);
        }
      }
    }
#pragma unroll
    for (int k = 0; k < NS; ++k) {
      if (k < kmax) {
        vout[(size_t)bs[k] * D_DIM + l]      = acc0[k];
        vout[(size_t)bs[k] * D_DIM + l + 64] = acc1[k];
      }
    }
  }
}

// ---------------- stage 2: w = R_src^T @ v; out = proj(mobius(proj(c_tgt), w))
__global__ __launch_bounds__(256) void k_stage2(
    const float* __restrict__ centers, const float* __restrict__ rot,
    const int* __restrict__ tgt_idx, const int* __restrict__ ws,
    float* __restrict__ io, int B)
{
  __shared__ float R[D_DIM * PADR];
  __shared__ float vs[4][NS][D_DIM];

  const int tid = threadIdx.x;
  const int chart = blockIdx.x >> 3;
  const int q = blockIdx.x & 7;
  const int n = ws[3*NCHART + chart];
  if (q * 4 * NS >= n) return;
  const int base = ws[2*NCHART + chart];
  const int* __restrict__ slist = ws + 4*NCHART + B;

  const f32x4* G4 = (const f32x4*)(rot + (size_t)chart * D_DIM * D_DIM);
  for (int g = tid; g < 4096; g += 256) {
    int r = g >> 5, J = g & 31;
    *(f32x4*)&R[r * PADR + 4 * J] = G4[g];
  }
  __syncthreads();

  const int w = tid >> 6, l = tid & 63;

  for (int s0 = (q * 4 + w) * NS; s0 < n; s0 += 32 * NS) {
    const int kmax = min(NS, n - s0);
    int bs[NS];
#pragma unroll
    for (int k = 0; k < NS; ++k) {
      if (k < kmax) {
        int b = slist[base + s0 + k];
        bs[k] = b;
        vs[w][k][l]      = io[(size_t)b * D_DIM + l];
        vs[w][k][l + 64] = io[(size_t)b * D_DIM + l + 64];
      }
    }
    asm volatile("s_waitcnt lgkmcnt(0)" ::: "memory");

    // w_i = sum_j R[j][i] v_j ; scalar j-loop, bounded unroll (round-5 structure),
    // column reads = 2 lanes/bank (free); NS=2 shares each R read.
    float acc0[NS] = {}, acc1[NS] = {};
#pragma unroll 8
    for (int j = 0; j < 128; ++j) {
      float r0 = R[j * PADR + l];
      float r1 = R[j * PADR + l + 64];
      float vj0 = vs[w][0][j];
      float vj1 = vs[w][1][j];
      acc0[0] = fmaf(r0, vj0, acc0[0]);
      acc1[0] = fmaf(r1, vj0, acc1[0]);
      acc0[1] = fmaf(r0, vj1, acc0[1]);
      acc1[1] = fmaf(r1, vj1, acc1[1]);
    }

#pragma unroll
    for (int k = 0; k < NS; ++k) {
      if (k < kmax) {
        int b = bs[k];
        int ti = tgt_idx[b];
        float c0 = centers[(size_t)ti * D_DIM + l];
        float c1 = centers[(size_t)ti * D_DIM + l + 64];
        float ncn = sqrtf(wave_sum(c0 * c0 + c1 * c1));
        if (ncn > MAXNORM) { float sc = MAXNORM / ncn; c0 *= sc; c1 *= sc; }

        float w0 = acc0[k], w1 = acc1[k];
        float x2 = wave_sum(c0 * c0 + c1 * c1);
        float y2 = wave_sum(w0 * w0 + w1 * w1);
        float xy = wave_sum(c0 * w0 + c1 * w1);
        float nx  = 1.0f + 2.0f * xy + y2;
        float ny  = 1.0f - x2;
        float inv = 1.0f / fmaxf(1.0f + 2.0f * xy + x2 * y2, 1e-15f);
        float o0 = (nx * c0 + ny * w0) * inv;
        float o1 = (nx * c1 + ny * w1) * inv;

        float no = sqrtf(wave_sum(o0 * o0 + o1 * o1));
        if (no > MAXNORM) { float sc = MAXNORM / no; o0 *= sc; o1 *= sc; }

        io[(size_t)b * D_DIM + l]      = o0;
        io[(size_t)b * D_DIM + l + 64] = o1;
      }
    }
  }
}

extern "C" void kernel_launch(void* const* d_in, const int* in_sizes, int n_in,
                              void* d_out, int out_size, void* d_ws, size_t ws_size,
                              hipStream_t stream) {
  const float* z_n     = (const float*)d_in[0];
  const float* centers = (const float*)d_in[1];
  const float* rot     = (const float*)d_in[2];
  const int*   src     = (const int*)d_in[3];
  const int*   tgt     = (const int*)d_in[4];
  float* out = (float*)d_out;
  int* ws = (int*)d_ws;
  const int B = in_sizes[3];

  k_setup<<<dim3(1), dim3(256), 0, stream>>>(src, tgt, ws, B);
  dim3 grid(NCHART * BPC), block(256);
  k_stage1<<<grid, block, 0, stream>>>(z_n, centers, rot, src, ws, out);
  k_stage2<<<grid, block, 0, stream>>>(centers, rot, tgt, ws, out, B);
}